// Round 15
// baseline (212.343 us; speedup 1.0000x reference)
//
#include <hip/hip_runtime.h>

// ---------------- problem constants ----------------
#define LQ   20197
#define MTOT 40394           // 2 * 20197

typedef _Float16 f16;
typedef _Float16 f16x8 __attribute__((ext_vector_type(8)));
typedef _Float16 f16x4 __attribute__((ext_vector_type(4)));
typedef _Float16 f16x2 __attribute__((ext_vector_type(2)));
typedef float    f32x4 __attribute__((ext_vector_type(4)));

// ---------------- workspace layout (bytes) ----------------
#define OFF_B4 1507328ull      // oa f16 [M,384] -> later y2h f16 [M,256]
#define OFF_B1 42870784ull     // src f16 (residual for LN1)
#define OFF_B2 63552512ull     // query f16 -> later x1h f16
#define OFF_B3 84234240ull     // valueT f16 [8][M][32]; later FFN hidden hh (B3..B7)
#define OFF_B5 104915968ull    // 128B pad (valueT pair-load overrun) + bias_oa f32 [384]
#define OFF_B6 125597696ull    // src2h f16 [M,256] (consumed before FFN1)
#define OFF_B7 166961152ull    // samph f16 [M,256] (consumed by out-proj GEMM)

// wT element offsets (f16 elements)
#define WT_V    0
#define WT_OFF  65536          // off rows [256][256] then attn rows [128][256] contiguous
#define WT_ATTN 131072
#define WT_OUT  163840
#define WT_W1   229376
#define WT_W2   491520
#define WT_TOTAL 753664
#define WCONV_TOTAL (WT_TOTAL + 384)
#define PREP_TOTAL (MTOT * 64)          // float4 groups
#define FUSED_TOTAL (WCONV_TOTAL + PREP_TOTAL)

// ---------------- async global->LDS, 16B per lane ----------------
__device__ __forceinline__ void gload_lds16(const f16* g, f16* l) {
    __builtin_amdgcn_global_load_lds(
        (const __attribute__((address_space(1))) unsigned int*)g,
        (__attribute__((address_space(3))) unsigned int*)l,
        16, 0, 0);
}

// ---------------- fused: weight transpose+convert + bias concat + prep ----------------
__global__ __launch_bounds__(256) void k_wconv_prep(
    const float* __restrict__ wv, const float* __restrict__ woff,
    const float* __restrict__ wattn, const float* __restrict__ wout,
    const float* __restrict__ w1, const float* __restrict__ w2,
    const float* __restrict__ boff, const float* __restrict__ battn,
    f16* __restrict__ dst, float* __restrict__ biasoa,
    const float* __restrict__ srcf, const float* __restrict__ posf,
    f16* __restrict__ srch, f16* __restrict__ qh)
{
    int gid = blockIdx.x * 256 + threadIdx.x;
    if (gid >= FUSED_TOTAL) return;
    if (gid >= WCONV_TOTAL) {
        const int i = gid - WCONV_TOTAL;
        float4 s = ((const float4*)srcf)[i];
        float4 p = ((const float4*)posf)[i];
        f16x4 hs = { (f16)s.x, (f16)s.y, (f16)s.z, (f16)s.w };
        f16x4 hq = { (f16)(s.x + p.x), (f16)(s.y + p.y), (f16)(s.z + p.z), (f16)(s.w + p.w) };
        ((f16x4*)srch)[i] = hs;
        ((f16x4*)qh)[i]   = hq;
        return;
    }
    if (gid >= WT_TOTAL) {
        int i = gid - WT_TOTAL;
        biasoa[i] = (i < 256) ? boff[i] : battn[i - 256];
        return;
    }
    const float* src; int Kd, Nd, base;
    if      (gid < 65536)  { src = wv;    Kd = 256;  Nd = 256;  base = 0; }
    else if (gid < 131072) { src = woff;  Kd = 256;  Nd = 256;  base = 65536; }
    else if (gid < 163840) { src = wattn; Kd = 256;  Nd = 128;  base = 131072; }
    else if (gid < 229376) { src = wout;  Kd = 256;  Nd = 256;  base = 163840; }
    else if (gid < 491520) { src = w1;    Kd = 256;  Nd = 1024; base = 229376; }
    else                   { src = w2;    Kd = 1024; Nd = 256;  base = 491520; }
    int loc = gid - base;
    int n = loc % Nd, k = loc / Nd;
    dst[base + n * Kd + k] = (f16)src[k * Nd + n];
}

// ---------------- GEMM 128x128 tile, BK=32, dbuf global_load_lds, XCD swizzle ----------------
// C[M,N] = A[M,K](f16) * Bt[N,K](f16)^T + bias ; N % 128 == 0 assumed.
// OUTM: 1 = f16 row-major [M][N], 2 = f16 head-blocked [N/32][M][32]
template<bool RELU, int OUTM>
__global__ __launch_bounds__(256) void k_gemm128(
    const f16* __restrict__ A, const f16* __restrict__ Bt,
    const float* __restrict__ bias, void* __restrict__ Cout,
    int M, int N, int K)
{
    __shared__ __align__(16) char pool[34816];   // staging 32KB  |  C-tile 128*136*2B
    f16* const sm = (f16*)pool;

    const int NBn = N >> 7;
    const int MBn = (M + 127) >> 7;
    const int tiles = MBn * NBn;
    const int q = gridDim.x >> 3;                 // grid padded to %8
    const int bid = blockIdx.x;
    const int swz = (bid & 7) * q + (bid >> 3);   // bijective XCD swizzle
    if (swz >= tiles) return;
    const int m0 = (swz / NBn) << 7;
    const int n0 = (swz % NBn) << 7;

    const int t = threadIdx.x, wid = t >> 6, lane = t & 63;

    const int c0 = wid, c1 = wid + 4;
    const int sr = lane >> 2, sk = (lane & 3) * 8;
    const int ra0 = min(m0 + c0 * 16 + sr, M - 1);
    const int ra1 = min(m0 + c1 * 16 + sr, M - 1);
    const f16* pa0 = A + (size_t)ra0 * K + sk;
    const f16* pa1 = A + (size_t)ra1 * K + sk;
    const f16* pb0 = Bt + (size_t)(n0 + c0 * 16 + sr) * K + sk;
    const f16* pb1 = Bt + (size_t)(n0 + c1 * 16 + sr) * K + sk;
    const int lo0 = c0 * 512, lo1 = c1 * 512;

    const int wr = wid >> 1, wc = wid & 1;
    const int fr = lane & 15, kb = (lane >> 4) * 8;

    f32x4 acc[4][4] = {};
    const int NT = K >> 5;

    gload_lds16(pa0, sm + lo0);
    gload_lds16(pa1, sm + lo1);
    gload_lds16(pb0, sm + 4096 + lo0);
    gload_lds16(pb1, sm + 4096 + lo1);
    __syncthreads();

    for (int tt = 0; tt < NT; ++tt) {
        const int cur = (tt & 1) << 13, nxt = cur ^ 8192;
        if (tt + 1 < NT) {
            const int k0 = (tt + 1) << 5;
            gload_lds16(pa0 + k0, sm + nxt + lo0);
            gload_lds16(pa1 + k0, sm + nxt + lo1);
            gload_lds16(pb0 + k0, sm + nxt + 4096 + lo0);
            gload_lds16(pb1 + k0, sm + nxt + 4096 + lo1);
        }
        f16x8 af[4], bf[4];
#pragma unroll
        for (int i = 0; i < 4; ++i)
            af[i] = *(const f16x8*)&sm[cur + (wr * 64 + i * 16 + fr) * 32 + kb];
#pragma unroll
        for (int i = 0; i < 4; ++i)
            bf[i] = *(const f16x8*)&sm[cur + 4096 + (wc * 64 + i * 16 + fr) * 32 + kb];
#pragma unroll
        for (int mi = 0; mi < 4; ++mi)
#pragma unroll
            for (int ni = 0; ni < 4; ++ni)
                acc[mi][ni] = __builtin_amdgcn_mfma_f32_16x16x32_f16(af[mi], bf[ni], acc[mi][ni], 0, 0, 0);
        __syncthreads();
    }

    // ---- epilogue: acc -> LDS (stride 136) -> coalesced global ----
    const int r4 = (lane >> 4) * 4;
#pragma unroll
    for (int ni = 0; ni < 4; ++ni) {
        const int lcol = wc * 64 + ni * 16 + fr;
        const float bv = bias[n0 + lcol];
#pragma unroll
        for (int mi = 0; mi < 4; ++mi) {
#pragma unroll
            for (int j = 0; j < 4; ++j) {
                float v = acc[mi][ni][j] + bv;
                if (RELU) v = fmaxf(v, 0.f);
                sm[(wr * 64 + mi * 16 + r4 + j) * 136 + lcol] = (f16)v;
            }
        }
    }
    __syncthreads();

    if (OUTM == 1) {
        const int rr = t >> 4, cc = (t & 15) * 8;
#pragma unroll
        for (int pass = 0; pass < 8; ++pass) {
            const int r = pass * 16 + rr;
            const int row = m0 + r;
            if (row < M) {
                f16x8 v = *(const f16x8*)&sm[r * 136 + cc];
                *(f16x8*)&((f16*)Cout)[(size_t)row * N + n0 + cc] = v;
            }
        }
    } else {
        const int cbl = t >> 6, rr = (t & 63) >> 2, cc = (t & 3) * 8;
        const size_t cb = (size_t)((n0 >> 5) + cbl);
#pragma unroll
        for (int pass = 0; pass < 8; ++pass) {
            const int r = pass * 16 + rr;
            const int row = m0 + r;
            if (row < M) {
                f16x8 v = *(const f16x8*)&sm[r * 136 + cbl * 32 + cc];
                *(f16x8*)&((f16*)Cout)[(cb * M + row) * 32 + cc] = v;
            }
        }
    }
}

// ---------------- fused softmax + deformable bilinear sampling ----------------
// HEAD-SPLIT (head = blockIdx.x & 7 -> XCD; slab 2.59MB < 4MB L2) +
// CORNER-PAIR loads (two contiguous 128B spans per corner quad, 8 lanes each) +
// PRE-ARRANGED weights: phase 1 stores per-xc pre-duplicated {wa,wa,wb,wb} f16x4,
// so phase 2's weight access is one 8B LDS broadcast-read, zero select/pack VALU.
__global__ __launch_bounds__(256) void k_sample(
    const f16* __restrict__ oa, const f16* __restrict__ valueT,
    const float* __restrict__ ref, f16* __restrict__ samp)
{
    __shared__ int2  s_g[32][17];       // (b00 signed bytes, dy6); pad 17 for banks
    __shared__ f16x4 s_wd[32][2][17];   // [tok][xc]: {wa,wa,wb,wb} premultiplied
    const int head = blockIdx.x & 7;
    const int tok0 = (blockIdx.x >> 3) * 32;
    const int t = threadIdx.x;

#pragma unroll
    for (int it = 0; it < 2; ++it) {
        const int tl = it * 16 + (t >> 4);
        const int lp = t & 15, l = lp >> 2;
        const int tok = tok0 + tl;
        if (tok < MTOT) {
            const size_t row = (size_t)tok * 384;
            float logit = (float)oa[row + 256 + head * 16 + lp];
            float mx = logit;
#pragma unroll
            for (int m = 1; m < 16; m <<= 1) mx = fmaxf(mx, __shfl_xor(mx, m));
            float e = __expf(logit - mx);
            float sum = e;
#pragma unroll
            for (int m = 1; m < 16; m <<= 1) sum += __shfl_xor(sum, m);
            const float aw = e / sum;

            const float fW = (l == 0) ? 152.f : (l == 1) ? 76.f : (l == 2) ? 38.f : 19.f;
            const float fH = (l == 0) ? 100.f : (l == 1) ? 50.f : (l == 2) ? 25.f : 13.f;
            const int   W  = (l == 0) ? 152 : (l == 1) ? 76 : (l == 2) ? 38 : 19;
            const int   H  = (l == 0) ? 100 : (l == 1) ? 50 : (l == 2) ? 25 : 13;
            const int   st = (l == 0) ? 0 : (l == 1) ? 15200 : (l == 2) ? 19000 : 19950;

            const f16x2 ov = *(const f16x2*)&oa[row + head * 32 + lp * 2];
            const float2 rxy = *(const float2*)&ref[(size_t)tok * 8 + l * 2];
            const float x = rxy.x * fW + (float)ov.x - 0.5f;
            const float y = rxy.y * fH + (float)ov.y - 0.5f;
            const float xf = floorf(x), yf = floorf(y);
            const float fx = x - xf, fy = y - yf;
            const int x0 = (int)xf, y0 = (int)yf;

            const bool vx0 = (x0 >= 0) && (x0 < W);
            const bool vx1 = (x0 >= -1) && (x0 < W - 1);
            const bool vy0 = (y0 >= 0) && (y0 < H);
            const bool vy1 = (y0 >= -1) && (y0 < H - 1);
            const int y0c = min(max(y0, 0), H - 1), y1c = min(max(y0 + 1, 0), H - 1);
            const int bx  = min(max(x0, -1), W - 1);   // pair base: bx=x0c (w00), bx+1=x1c (w01)

            const int n = (tok >= LQ) ? 1 : 0;
            const int b00 = (n * LQ + st + y0c * W + bx) << 6;       // signed, can be -64
            const int dy6 = ((y1c - y0c) * W) << 6;                  // 0 or W*64
            s_g[tl][lp] = make_int2(b00, dy6);

            const f16 w00 = (f16)((vx0 && vy0) ? (1.f - fx) * (1.f - fy) * aw : 0.f);
            const f16 w01 = (f16)((vx1 && vy0) ? fx * (1.f - fy) * aw : 0.f);
            const f16 w10 = (f16)((vx0 && vy1) ? (1.f - fx) * fy * aw : 0.f);
            const f16 w11 = (f16)((vx1 && vy1) ? fx * fy * aw : 0.f);
            f16x4 wd0 = { w00, w00, w10, w10 };   // xc=0: y0-weight dup, y1-weight dup
            f16x4 wd1 = { w01, w01, w11, w11 };   // xc=1
            s_wd[tl][0][lp] = wd0;
            s_wd[tl][1][lp] = wd1;
        }
    }
    __syncthreads();

    const int tl = t >> 3;            // 32 tokens
    const int g3 = t & 7;             // 8 lanes per (tok,head): 128B span
    const int xc = g3 >> 2;           // x-corner half
    const int l4 = g3 & 3;            // dim quarter within the 64B entry
    const int tok = tok0 + tl;
    if (tok >= MTOT) return;
    const int lb = g3 * 16;           // byte offset within the 128B pair span
    const char* vbase = (const char*)valueT + (size_t)head * (MTOT * 64ull);

    f16x2 a0 = {}, a1 = {}, a2 = {}, a3 = {};
#pragma unroll 4
    for (int p = 0; p < 16; ++p) {
        const int2  g  = s_g[tl][p];
        const f16x4 wd = s_wd[tl][xc][p];
        const char* base = vbase + (g.x + lb);
        const f16x8 vA = *(const f16x8*)(base);          // y0-row span (coalesced 128B/8 lanes)
        const f16x8 vB = *(const f16x8*)(base + g.y);    // y1-row span
        const f16x2 wA = { wd[0], wd[1] };               // {wa,wa} — free subregister alias
        const f16x2 wB = { wd[2], wd[3] };               // {wb,wb}
        const f16x2* pA = (const f16x2*)&vA;
        const f16x2* pB = (const f16x2*)&vB;
        a0 = a0 + pA[0] * wA; a1 = a1 + pA[1] * wA;
        a2 = a2 + pA[2] * wA; a3 = a3 + pA[3] * wA;
        a0 = a0 + pB[0] * wB; a1 = a1 + pB[1] * wB;
        a2 = a2 + pB[2] * wB; a3 = a3 + pB[3] * wB;
    }

    // pair-reduce across the two x-corner halves (partner lane t^4, same wave)
    union { f16x2 h; int i; } u0, u1, u2, u3;
    u0.h = a0; u1.h = a1; u2.h = a2; u3.h = a3;
    union { int i; f16x2 h; } r0, r1, r2, r3;
    r0.i = __shfl_xor(u0.i, 4); r1.i = __shfl_xor(u1.i, 4);
    r2.i = __shfl_xor(u2.i, 4); r3.i = __shfl_xor(u3.i, 4);
    a0 = a0 + r0.h; a1 = a1 + r1.h; a2 = a2 + r2.h; a3 = a3 + r3.h;

    // each half writes 4 dims (8B, coalesced)
    f16x4 o = xc ? (f16x4){ a2.x, a2.y, a3.x, a3.y }
                 : (f16x4){ a0.x, a0.y, a1.x, a1.y };
    *(f16x4*)&samp[(size_t)tok * 256 + head * 32 + l4 * 8 + xc * 4] = o;
}

// ---------------- LN (f16 inputs): y = LN(xa + xb)*g + b ----------------
// OUTF16=1 -> write f16, else f32
template<int OUTF16>
__global__ __launch_bounds__(256) void k_lnh(
    const f16* __restrict__ xa, const f16* __restrict__ xb,
    const float* __restrict__ g, const float* __restrict__ be,
    void* __restrict__ y, int M)
{
    const int row = blockIdx.x * 4 + (threadIdx.x >> 6);
    const int lane = threadIdx.x & 63;
    if (row >= M) return;
    const size_t o = (size_t)row * 256 + lane * 4;
    f16x4 a = *(const f16x4*)(xa + o);
    f16x4 b = *(const f16x4*)(xb + o);
    float x0 = (float)a.x + (float)b.x, x1 = (float)a.y + (float)b.y;
    float x2 = (float)a.z + (float)b.z, x3 = (float)a.w + (float)b.w;
    float s  = x0 + x1 + x2 + x3;
    float ss = x0*x0 + x1*x1 + x2*x2 + x3*x3;
#pragma unroll
    for (int m = 1; m < 64; m <<= 1) { s += __shfl_xor(s, m); ss += __shfl_xor(ss, m); }
    const float mean = s * (1.f / 256.f);
    const float var  = ss * (1.f / 256.f) - mean * mean;
    const float rstd = rsqrtf(var + 1e-5f);
    float4 gv = *(const float4*)(g + lane * 4);
    float4 bv = *(const float4*)(be + lane * 4);
    const float y0 = (x0 - mean) * rstd * gv.x + bv.x;
    const float y1 = (x1 - mean) * rstd * gv.y + bv.y;
    const float y2 = (x2 - mean) * rstd * gv.z + bv.z;
    const float y3 = (x3 - mean) * rstd * gv.w + bv.w;
    if (OUTF16) {
        f16x4 hv = { (f16)y0, (f16)y1, (f16)y2, (f16)y3 };
        *(f16x4*)((f16*)y + o) = hv;
    } else {
        float4 yo = { y0, y1, y2, y3 };
        *(float4*)((float*)y + o) = yo;
    }
}

// ---------------- launch ----------------
extern "C" void kernel_launch(void* const* d_in, const int* in_sizes, int n_in,
                              void* d_out, int out_size, void* d_ws, size_t ws_size,
                              hipStream_t stream) {
    const float* src   = (const float*)d_in[0];
    const float* pos   = (const float*)d_in[1];
    const float* ref   = (const float*)d_in[2];
    const float* w_value = (const float*)d_in[5];
    const float* b_value = (const float*)d_in[6];
    const float* w_off   = (const float*)d_in[7];
    const float* b_off   = (const float*)d_in[8];
    const float* w_attn  = (const float*)d_in[9];
    const float* b_attn  = (const float*)d_in[10];
    const float* w_out   = (const float*)d_in[11];
    const float* b_out   = (const float*)d_in[12];
    const float* g1    = (const float*)d_in[13];
    const float* beta1 = (const float*)d_in[14];
    const float* w1    = (const float*)d_in[15];
    const float* b1    = (const float*)d_in[16];
    const float* w2    = (const float*)d_in[17];
    const float* b2    = (const float*)d_in[18];
    const float* g2    = (const float*)d_in[19];
    const float* beta2 = (const float*)d_in[20];

    char* ws = (char*)d_ws;
    f16*   wT      = (f16*)(ws + 0);
    f16*   oa      = (f16*)(ws + OFF_B4);     // fused off|attn f16 [M,384]
    f16*   y2h     = (f16*)(ws + OFF_B4);     // later: FFN2 out f16 [M,256] (oa dead)
    f16*   srch    = (f16*)(ws + OFF_B1);     // src f16 (residual for LN1)
    f16*   qh      = (f16*)(ws + OFF_B2);     // query f16
    f16*   x1h     = (f16*)(ws + OFF_B2);     // later: LN1 out f16 (qh dead)
    f16*   valueT  = (f16*)(ws + OFF_B3);     // value f16 head-blocked [8][M][32]
    f16*   hh      = (f16*)(ws + OFF_B3);     // later: FFN hidden f16 [M,1024] (B3..B7)
    float* biasoa  = (float*)(ws + OFF_B5 + 128);  // concat bias f32 [384], after 128B pad
    f16*   src2h   = (f16*)(ws + OFF_B6);     // attn output f16 [M,256]
    f16*   samph   = (f16*)(ws + OFF_B7);     // sampled out f16 [M,256]
    float* outp    = (float*)d_out;

    const int M = MTOT;
    const int MB = (M + 127) / 128;
    auto grid8 = [&](int nb) { return ((MB * nb) + 7) & ~7; };   // pad to %8 for swizzle

    // fused weight-convert + bias-concat + prep (one dispatch)
    k_wconv_prep<<<(FUSED_TOTAL + 255) / 256, 256, 0, stream>>>(
        w_value, w_off, w_attn, w_out, w1, w2, b_off, b_attn, wT, biasoa,
        src, pos, srch, qh);

    // value = src @ w_value + b_value -> head-blocked f16
    k_gemm128<false, 2><<<grid8(2), 256, 0, stream>>>(srch, wT + WT_V, b_value, valueT, M, 256, 256);
    // fused off|attn logits -> f16 [M,384]
    k_gemm128<false, 1><<<grid8(3), 256, 0, stream>>>(qh, wT + WT_OFF, biasoa, oa, M, 384, 256);
    // softmax + bilinear sampling: head-split + corner-pair loads (32 tok/block)
    {
        const int nchunk = (MTOT + 31) / 32;   // 1263
        k_sample<<<dim3(nchunk * 8), 256, 0, stream>>>(oa, valueT, ref, samph);
    }
    // out projection -> src2 f16
    k_gemm128<false, 1><<<grid8(2), 256, 0, stream>>>(samph, wT + WT_OUT, b_out, src2h, M, 256, 256);
    // LN1: x1h = LN(srch + src2h) f16
    k_lnh<1><<<(M + 3) / 4, 256, 0, stream>>>(srch, src2h, g1, beta1, x1h, M);
    // FFN1: h = relu(x1 @ w1 + b1) f16
    k_gemm128<true, 1><<<grid8(8), 256, 0, stream>>>(x1h, wT + WT_W1, b1, hh, M, 1024, 256);
    // FFN2: y2 = h @ w2 + b2 -> f16
    k_gemm128<false, 1><<<grid8(2), 256, 0, stream>>>(hh, wT + WT_W2, b2, y2h, M, 256, 1024);
    // LN2 -> d_out f32
    k_lnh<0><<<(M + 3) / 4, 256, 0, stream>>>(x1h, y2h, g2, beta2, outp, M);

    (void)in_sizes; (void)n_in; (void)out_size; (void)ws_size;
}